// Round 2
// 3795.142 us; speedup vs baseline: 2.3509x; 2.3509x over previous
//
#include <hip/hip_runtime.h>
#include <math.h>

// ---------------------------------------------------------------------------
// fp16x3 split-precision MFMA rewrite of the spectral GEMM chain.
// All intermediates feature-major [C][N]. Two B-operand matrices:
//   VT[n][k] = V[k][n]  (for T = V^T X  "TN" GEMMs, MODE 0 epilogue)
//   Vr[n][k] = V[n][k]  (for Y = V B    "NN" GEMMs, MODE 1 epilogue)
// lo parts scaled by 2048 to stay in f16 normal range.
// Workspace requirement: ~950 MB.
// ---------------------------------------------------------------------------

#define NN     10000
#define KP     10048          // K padded to 157*64
#define NRPAD  10112          // B rows padded to 79*128
#define FIN    128
#define NHID   128
#define PIF    3.14159265358979323846f
#define LOSC   2048.0f
#define ILOSC  (1.0f/2048.0f)

typedef _Float16 f16x8 __attribute__((ext_vector_type(8)));
typedef _Float16 f16x4 __attribute__((ext_vector_type(4)));
typedef float    f32x4 __attribute__((ext_vector_type(4)));

__device__ __forceinline__ float lrelu(float x) { return x > 0.f ? x : 0.2f * x; }

__device__ __forceinline__ void split16(float v, _Float16* hi, _Float16* lo) {
    _Float16 h = (_Float16)v;
    *hi = h;
    *lo = (_Float16)((v - (float)h) * LOSC);
}

__device__ __forceinline__ void gload16(const void* g, void* l) {
    __builtin_amdgcn_global_load_lds((const __attribute__((address_space(1))) void*)g,
                                     (__attribute__((address_space(3))) void*)l, 16, 0, 0);
}

// ---------------- filters: phi(8l), psi(l/4), psi(l/2) per node ----------------
__global__ void k_filters(const float* __restrict__ lamb, float* __restrict__ filt) {
    int i = blockIdx.x * blockDim.x + threadIdx.x;
    if (i >= NN) return;
    float l = lamb[i];
    float a = 8.f * l; if (a == 0.f) a = 1e-7f;
    float ya = 2.f * PIF * a;
    filt[i] = sinf(ya) / ya;
    float b = l * 0.25f; if (b == 0.f) b = 1e-8f;
    filt[NN + i] = sinf(b) / (PIF * b) * (1.f - cosf(b));
    float c = l * 0.5f; if (c == 0.f) c = 1e-8f;
    filt[2 * NN + i] = sinf(c) / (PIF * c) * (1.f - cosf(c));
}

// ---------------- V^T -> f16 hi/lo, [NRPAD][KP], pads zeroed ----------------
__global__ __launch_bounds__(256) void k_buildVT(const float* __restrict__ V,
                                                 _Float16* __restrict__ VTh,
                                                 _Float16* __restrict__ VTl) {
    __shared__ float t[32][33];
    int tx = threadIdx.x, ty = threadIdx.y;   // 32 x 8
    int k0 = blockIdx.x * 32, n0 = blockIdx.y * 32;
#pragma unroll
    for (int i = 0; i < 4; i++) {
        int k = k0 + ty * 4 + i, n = n0 + tx;
        t[ty * 4 + i][tx] = (k < NN && n < NN) ? V[(size_t)k * NN + n] : 0.f;
    }
    __syncthreads();
#pragma unroll
    for (int i = 0; i < 4; i++) {
        int n = n0 + ty * 4 + i, k = k0 + tx;
        if (n < NRPAD && k < KP) {
            _Float16 h, l; split16(t[tx][ty * 4 + i], &h, &l);
            VTh[(size_t)n * KP + k] = h;
            VTl[(size_t)n * KP + k] = l;
        }
    }
}

// ---------------- Vr = V straight copy -> f16 hi/lo, [NRPAD][KP], pads zeroed --
__global__ __launch_bounds__(256) void k_buildVr(const float* __restrict__ V,
                                                 _Float16* __restrict__ Vrh,
                                                 _Float16* __restrict__ Vrl) {
    int t = blockIdx.x * 256 + threadIdx.x;   // over NRPAD * (KP/4)
    const int KQ = KP / 4;
    int n = t / KQ;
    if (n >= NRPAD) return;
    int k4 = (t - n * KQ) * 4;
    float4 v = make_float4(0.f, 0.f, 0.f, 0.f);
    if (n < NN && k4 < NN)   // k4 < NN implies k4+3 <= 9999 < NN
        v = *(const float4*)(V + (size_t)n * NN + k4);
    f16x4 h, l;
    _Float16 hh, ll;
    split16(v.x, &hh, &ll); h[0] = hh; l[0] = ll;
    split16(v.y, &hh, &ll); h[1] = hh; l[1] = ll;
    split16(v.z, &hh, &ll); h[2] = hh; l[2] = ll;
    split16(v.w, &hh, &ll); h[3] = hh; l[3] = ll;
    *(f16x4*)(Vrh + (size_t)n * KP + k4) = h;
    *(f16x4*)(Vrl + (size_t)n * KP + k4) = l;
}

// ---------------- h^T = (x @ W1 + b1)^T as f16 hi/lo [128][KP] ----------------
__global__ __launch_bounds__(256) void k_xw1t(const float* __restrict__ x, const float* __restrict__ W1,
                                              const float* __restrict__ b1,
                                              _Float16* __restrict__ hTh, _Float16* __restrict__ hTl) {
    int n = blockIdx.x * 256 + threadIdx.x;
    int c = blockIdx.y;
    if (n >= KP) return;
    float acc = 0.f;
    if (n < NN) {
        acc = b1[c];
        const float* xr = x + (size_t)n * FIN;
#pragma unroll 4
        for (int k = 0; k < FIN; k++) acc += xr[k] * W1[k * NHID + c];
    }
    _Float16 h, l; split16(acc, &h, &l);
    hTh[(size_t)c * KP + n] = h;
    hTl[(size_t)c * KP + n] = l;
}

// ---------------- fp16x3 MFMA GEMM: D[c][n] = sum_k A[c][k] * Bbuf[n][k] ----
// MODE 0 (B = VT): epilogue multiplies by NF filters -> OutH/OutL rows f*C + c
// MODE 1 (B = Vr): epilogue writes Dy fp32 [C][NN]; rows >= absStart also write
// |v| f16 pairs to XaH/XaL (rows c-absStart). Pad cols [NN,KP) written as 0.
template<int MODE, int NF>
__global__ __launch_bounds__(256, 2) void k_mfma(
    const _Float16* __restrict__ Ah, const _Float16* __restrict__ Al,
    const _Float16* __restrict__ Bh, const _Float16* __restrict__ Bl,
    int C,
    const float* __restrict__ filt,
    _Float16* __restrict__ OutH, _Float16* __restrict__ OutL,
    float* __restrict__ Dy, int absStart,
    _Float16* __restrict__ XaH, _Float16* __restrict__ XaL)
{
    __shared__ __align__(16) _Float16 sAh[128 * 64];
    __shared__ __align__(16) _Float16 sAl[128 * 64];
    __shared__ __align__(16) _Float16 sBh[128 * 64];
    __shared__ __align__(16) _Float16 sBl[128 * 64];

    const int tid  = threadIdx.x;
    const int lane = tid & 63;
    const int wave = tid >> 6;
    const int arow0 = blockIdx.x * 128;
    const int brow0 = blockIdx.y * 128;

    // staging: per wave 4 chunks of 1KB per array; source k-chunk pre-swizzled
    // (c_src = c_lds ^ (row&7)) so linear LDS dest ends up XOR-swizzled for
    // conflict-free ds_read_b128.
    const int lrow = lane >> 3;                  // 0..7
    const int kcol = ((lane & 7) ^ lrow) << 3;   // swizzled k offset (halves)
    size_t offA[4], offB[4];
#pragma unroll
    for (int r = 0; r < 4; ++r) {
        int rit = wave * 32 + r * 8 + lrow;      // 0..127
        offA[r] = (size_t)(arow0 + rit) * KP + kcol;
        offB[r] = (size_t)(brow0 + rit) * KP + kcol;
    }

    f32x4 acc1[4][4], acc2[4][4];
#pragma unroll
    for (int i = 0; i < 4; ++i)
#pragma unroll
        for (int j = 0; j < 4; ++j) { acc1[i][j] = 0.f; acc2[i][j] = 0.f; }

    const int fr = lane & 15;
    const int fg = lane >> 4;
    const int wr = (wave >> 1) * 64;
    const int wc = (wave & 1) * 64;

    for (int kt = 0; kt < KP / 64; ++kt) {
        const size_t ko = (size_t)kt * 64;
#pragma unroll
        for (int r = 0; r < 4; ++r) {
            int cc = (wave * 4 + r) * 512;
            gload16(Ah + offA[r] + ko, sAh + cc);
            gload16(Al + offA[r] + ko, sAl + cc);
            gload16(Bh + offB[r] + ko, sBh + cc);
            gload16(Bl + offB[r] + ko, sBl + cc);
        }
        __syncthreads();   // compiler drains vmcnt before s_barrier
#pragma unroll
        for (int ki = 0; ki < 2; ++ki) {
            const int cs = ((((ki << 2) | fg)) ^ (fr & 7)) << 3;
            f16x8 ah[4], al[4], bh[4], bl[4];
#pragma unroll
            for (int mt = 0; mt < 4; ++mt) {
                int off = (wr + mt * 16 + fr) * 64 + cs;
                ah[mt] = *(const f16x8*)(sAh + off);
                al[mt] = *(const f16x8*)(sAl + off);
            }
#pragma unroll
            for (int nt = 0; nt < 4; ++nt) {
                int off = (wc + nt * 16 + fr) * 64 + cs;
                bh[nt] = *(const f16x8*)(sBh + off);
                bl[nt] = *(const f16x8*)(sBl + off);
            }
#pragma unroll
            for (int mt = 0; mt < 4; ++mt)
#pragma unroll
                for (int nt = 0; nt < 4; ++nt) {
                    acc1[mt][nt] = __builtin_amdgcn_mfma_f32_16x16x32_f16(ah[mt], bh[nt], acc1[mt][nt], 0, 0, 0);
                    acc2[mt][nt] = __builtin_amdgcn_mfma_f32_16x16x32_f16(ah[mt], bl[nt], acc2[mt][nt], 0, 0, 0);
                    acc2[mt][nt] = __builtin_amdgcn_mfma_f32_16x16x32_f16(al[mt], bh[nt], acc2[mt][nt], 0, 0, 0);
                }
        }
        __syncthreads();
    }

    // epilogue: C/D layout col = lane&15, row = (lane>>4)*4 + reg
    const int ccol  = lane & 15;
    const int crow0 = (lane >> 4) * 4;
#pragma unroll
    for (int nt = 0; nt < 4; ++nt) {
        int n = brow0 + wc + nt * 16 + ccol;
        if (n >= KP) continue;
        bool valid = n < NN;
        float f0 = 0.f, f1 = 0.f, f2 = 0.f;
        if (MODE == 0 && valid) {
            f0 = filt[n];
            if (NF > 1) { f1 = filt[NN + n]; f2 = filt[2 * NN + n]; }
        }
#pragma unroll
        for (int mt = 0; mt < 4; ++mt) {
            int cb = arow0 + wr + mt * 16 + crow0;
#pragma unroll
            for (int r = 0; r < 4; ++r) {
                float v = acc1[mt][nt][r] + acc2[mt][nt][r] * ILOSC;
                int c = cb + r;
                if (MODE == 0) {
#pragma unroll
                    for (int f = 0; f < NF; ++f) {
                        float fv = (f == 0 ? f0 : (f == 1 ? f1 : f2)) * v;
                        _Float16 h, l; split16(fv, &h, &l);
                        size_t o = (size_t)(f * C + c) * KP + n;
                        OutH[o] = h; OutL[o] = l;
                    }
                } else {
                    if (valid) Dy[(size_t)c * NN + n] = v;
                    if (c >= absStart) {
                        float av = valid ? fabsf(v) : 0.f;
                        _Float16 h, l; split16(av, &h, &l);
                        size_t o = (size_t)(c - absStart) * KP + n;
                        XaH[o] = h; XaL[o] = l;
                    }
                }
            }
        }
    }
}

// ---------------- r2[n,0:32] += Dy[c0:c0+C, n]^T @ W[0:C, 0:32] ----------------
__global__ void k_y2h2(const float* __restrict__ Yt, int c0, int C,
                       const float* __restrict__ Wp, float* __restrict__ r2) {
    int t = blockIdx.x * blockDim.x + threadIdx.x;
    if (t >= NN * 32) return;
    int n = t >> 5, j = t & 31;
    float acc = 0.f;
    for (int k = 0; k < C; k++) acc += Yt[(size_t)(c0 + k) * NN + n] * Wp[k * 32 + j];
    r2[t] += acc;
}

__global__ void k_zero_f(float* p, int n) {
    int i = blockIdx.x * blockDim.x + threadIdx.x;
    if (i < n) p[i] = 0.f;
}

// ---------------- CSR build ----------------
__global__ void k_zero_int(int* p, int n) {
    int i = blockIdx.x * blockDim.x + threadIdx.x;
    if (i < n) p[i] = 0;
}
__global__ void k_count(const int* __restrict__ dst, int* __restrict__ deg, int E) {
    int e = blockIdx.x * blockDim.x + threadIdx.x;
    if (e < E) atomicAdd(&deg[dst[e]], 1);
}
__global__ __launch_bounds__(1024) void k_scan(const int* __restrict__ deg,
                                               int* __restrict__ rowp, int* __restrict__ cur, int E) {
    __shared__ int s[1024];
    int t = threadIdx.x;
    int base = t * 10;
    int sum = 0;
    for (int i = 0; i < 10; i++) { int idx = base + i; if (idx < NN) sum += deg[idx]; }
    s[t] = sum; __syncthreads();
    for (int off = 1; off < 1024; off <<= 1) {
        int v = (t >= off) ? s[t - off] : 0;
        __syncthreads();
        s[t] += v;
        __syncthreads();
    }
    int run = (t > 0) ? s[t - 1] : 0;
    for (int i = 0; i < 10; i++) {
        int idx = base + i;
        if (idx < NN) { rowp[idx] = run; cur[idx] = run; run += deg[idx]; }
    }
    if (t == 0) rowp[NN] = E;
}
__global__ void k_fill(const int* __restrict__ src, const int* __restrict__ dst,
                       int* __restrict__ cur, int* __restrict__ csr, int E) {
    int e = blockIdx.x * blockDim.x + threadIdx.x;
    if (e < E) {
        int d = dst[e];
        int p = atomicAdd(&cur[d], 1);
        csr[p] = src[e];
    }
}

// ---------------- h2[n,j] = sum over in-edges r2[src,j]  (32 feat) ----------------
__global__ void k_agg32(const float* __restrict__ r2, const int* __restrict__ rowp,
                        const int* __restrict__ csr, float* __restrict__ h2) {
    int t = blockIdx.x * blockDim.x + threadIdx.x;
    if (t >= NN * 32) return;
    int n = t >> 5, j = t & 31;
    int s0 = rowp[n], s1 = rowp[n + 1];
    float a = 0.f;
    for (int e = s0; e < s1; e++) a += r2[(size_t)csr[e] * 32 + j];
    h2[t] = a;
}

// ---------------- attention logits per node/head ----------------
__global__ void k_att(const float* __restrict__ h2, const float* __restrict__ att_s,
                      const float* __restrict__ att_d, float* __restrict__ asrc,
                      float* __restrict__ adst) {
    int t = blockIdx.x * blockDim.x + threadIdx.x;
    if (t >= NN * 2) return;
    int n = t >> 1, hh = t & 1;
    const float* hr = h2 + (size_t)n * 32 + hh * 16;
    float s = 0.f, d = 0.f;
    for (int c = 0; c < 16; c++) {
        float v = hr[c];
        s += v * att_s[hh * 16 + c];
        d += v * att_d[hh * 16 + c];
    }
    asrc[t] = s; adst[t] = d;
}

// ---------------- GAT softmax-aggregate, one 64-thread block per dst ----------------
__global__ __launch_bounds__(64) void k_gat(const float* __restrict__ h2,
                                            const float* __restrict__ asrc,
                                            const float* __restrict__ adst,
                                            const int* __restrict__ rowp,
                                            const int* __restrict__ csr,
                                            const float* __restrict__ bias,
                                            float* __restrict__ gout) {
    int d = blockIdx.x, lane = threadIdx.x;
    int s0 = rowp[d], s1 = rowp[d + 1];
    __shared__ float sm[2], sden[2];
    int hh = lane >> 5;
    float adh = adst[d * 2 + hh];
    float eself = lrelu(asrc[d * 2 + hh] + adh);
    float m = eself;
    for (int j = s0 + (lane & 31); j < s1; j += 32) {
        int s = csr[j];
        m = fmaxf(m, lrelu(asrc[s * 2 + hh] + adh));
    }
    for (int off = 16; off; off >>= 1) m = fmaxf(m, __shfl_xor(m, off, 32));
    float den = ((lane & 31) == 0) ? expf(eself - m) : 0.f;
    for (int j = s0 + (lane & 31); j < s1; j += 32) {
        int s = csr[j];
        den += expf(lrelu(asrc[s * 2 + hh] + adh) - m);
    }
    for (int off = 16; off; off >>= 1) den += __shfl_xor(den, off, 32);
    if ((lane & 31) == 0) { sm[hh] = m; sden[hh] = den; }
    __syncthreads();
    int f = lane & 31;
    int h3 = f >> 4;
    float mh = sm[h3], dh = sden[h3];
    float ad3 = adst[d * 2 + h3];
    float acc = 0.f;
    for (int j = s0 + (lane >> 5); j < s1; j += 2) {
        int s = csr[j];
        float e = lrelu(asrc[s * 2 + h3] + ad3);
        acc += expf(e - mh) * h2[(size_t)s * 32 + f];
    }
    if ((lane >> 5) == 0) {
        float es = lrelu(asrc[d * 2 + h3] + ad3);
        acc += expf(es - mh) * h2[(size_t)d * 32 + f];
    }
    acc += __shfl_down(acc, 32, 64);
    if (lane < 32) gout[(size_t)d * 32 + f] = acc / dh + bias[f];
}

// ---------------- g = elu(gout) @ mlp_W + mlp_b ----------------
__global__ void k_mlp(const float* __restrict__ gout, const float* __restrict__ mw,
                      const float* __restrict__ mb, float* __restrict__ g) {
    int t = blockIdx.x * blockDim.x + threadIdx.x;
    if (t >= NN * 16) return;
    int n = t >> 4, j = t & 15;
    const float* gr = gout + (size_t)n * 32;
    float acc = mb[j];
    for (int k = 0; k < 32; k++) {
        float v = gr[k];
        v = v > 0.f ? v : expm1f(v);
        acc += v * mw[k * 16 + j];
    }
    g[t] = acc;
}

// ---------------- final edge-sum + log_softmax (fp32 output) ----------------
__global__ __launch_bounds__(64) void k_final(const float* __restrict__ g,
                                              const int* __restrict__ rowp,
                                              const int* __restrict__ csr,
                                              float* __restrict__ out) {
    int d = blockIdx.x, lane = threadIdx.x;
    int s0 = rowp[d], s1 = rowp[d + 1];
    int f = lane & 15, grp = lane >> 4;
    float acc = 0.f;
    for (int j = s0 + grp; j < s1; j += 4) acc += g[(size_t)csr[j] * 16 + f];
    acc += __shfl_xor(acc, 16, 64);
    acc += __shfl_xor(acc, 32, 64);
    float mx = acc;
    for (int off = 8; off; off >>= 1) mx = fmaxf(mx, __shfl_xor(mx, off, 16));
    float ex = expf(acc - mx);
    float se = ex;
    for (int off = 8; off; off >>= 1) se += __shfl_xor(se, off, 16);
    if (lane < 16) out[(size_t)d * 16 + f] = acc - mx - logf(se);
}

extern "C" void kernel_launch(void* const* d_in, const int* in_sizes, int n_in,
                              void* d_out, int out_size, void* d_ws, size_t ws_size,
                              hipStream_t stream) {
    (void)n_in; (void)out_size; (void)ws_size;
    const float* x       = (const float*)d_in[0];
    const int*   ei      = (const int*)d_in[1];
    const float* lamb    = (const float*)d_in[2];
    const float* V       = (const float*)d_in[3];
    const float* W1      = (const float*)d_in[4];
    const float* b1      = (const float*)d_in[5];
    const float* gat_W   = (const float*)d_in[6];
    const float* att_src = (const float*)d_in[7];
    const float* att_dst = (const float*)d_in[8];
    const float* gat_b   = (const float*)d_in[9];
    const float* mlp_W   = (const float*)d_in[10];
    const float* mlp_b   = (const float*)d_in[11];
    float* out = (float*)d_out;
    const int E = in_sizes[1] / 2;
    const int* e_src = ei;
    const int* e_dst = ei + E;

    char* w = (char*)d_ws;
    auto alloc = [&](size_t bytes) { void* p = (void*)w; w += (bytes + 255) & ~(size_t)255; return p; };
    _Float16* VTh  = (_Float16*)alloc((size_t)NRPAD * KP * 2);   // 203 MB
    _Float16* VTl  = (_Float16*)alloc((size_t)NRPAD * KP * 2);   // 203 MB
    _Float16* Vrh  = (_Float16*)alloc((size_t)NRPAD * KP * 2);   // 203 MB
    _Float16* Vrl  = (_Float16*)alloc((size_t)NRPAD * KP * 2);   // 203 MB
    _Float16* hTh  = (_Float16*)alloc((size_t)128 * KP * 2);
    _Float16* hTl  = (_Float16*)alloc((size_t)128 * KP * 2);
    _Float16* Bb0h = (_Float16*)alloc((size_t)384 * KP * 2);
    _Float16* Bb0l = (_Float16*)alloc((size_t)384 * KP * 2);
    _Float16* Xa1h = (_Float16*)alloc((size_t)256 * KP * 2);
    _Float16* Xa1l = (_Float16*)alloc((size_t)256 * KP * 2);
    _Float16* Bb1h = (_Float16*)alloc((size_t)768 * KP * 2);
    _Float16* Bb1l = (_Float16*)alloc((size_t)768 * KP * 2);
    _Float16* Xa2h = (_Float16*)alloc((size_t)512 * KP * 2);
    _Float16* Xa2l = (_Float16*)alloc((size_t)512 * KP * 2);
    _Float16* Bb2h = (_Float16*)alloc((size_t)512 * KP * 2);
    _Float16* Bb2l = (_Float16*)alloc((size_t)512 * KP * 2);
    float* Dy   = (float*)alloc((size_t)768 * NN * 4);           // 30.7 MB
    float* r2   = (float*)alloc((size_t)NN * 32 * 4);
    float* h2   = (float*)alloc((size_t)NN * 32 * 4);
    float* asrc = (float*)alloc((size_t)NN * 2 * 4);
    float* adst = (float*)alloc((size_t)NN * 2 * 4);
    float* gout = (float*)alloc((size_t)NN * 32 * 4);
    float* g    = (float*)alloc((size_t)NN * 16 * 4);
    float* filt = (float*)alloc((size_t)3 * NN * 4);
    int* deg    = (int*)alloc((size_t)NN * 4);
    int* rowp   = (int*)alloc((size_t)(NN + 1) * 4);
    int* cur    = (int*)alloc((size_t)NN * 4);
    int* csr    = (int*)alloc((size_t)E * 4);

    // CSR build
    k_zero_int<<<(NN + 255) / 256, 256, 0, stream>>>(deg, NN);
    k_count<<<(E + 255) / 256, 256, 0, stream>>>(e_dst, deg, E);
    k_scan<<<1, 1024, 0, stream>>>(deg, rowp, cur, E);
    k_fill<<<(E + 255) / 256, 256, 0, stream>>>(e_src, e_dst, cur, csr, E);

    k_filters<<<(NN + 255) / 256, 256, 0, stream>>>(lamb, filt);
    k_buildVT<<<dim3(KP / 32, NRPAD / 32), dim3(32, 8), 0, stream>>>(V, VTh, VTl);
    {
        long long tot = (long long)NRPAD * (KP / 4);
        k_buildVr<<<(int)((tot + 255) / 256), 256, 0, stream>>>(V, Vrh, Vrl);
    }
    k_xw1t<<<dim3((KP + 255) / 256, NHID), 256, 0, stream>>>(x, W1, b1, hTh, hTl);
    k_zero_f<<<(NN * 32 + 255) / 256, 256, 0, stream>>>(r2, NN * 32);

    const int NT = NRPAD / 128;  // 79 node tiles

    // ---- Level 0 ----
    k_mfma<0, 3><<<dim3(128 / 128, NT), 256, 0, stream>>>(hTh, hTl, VTh, VTl, 128, filt,
                                                          Bb0h, Bb0l, nullptr, 0, nullptr, nullptr);
    k_mfma<1, 0><<<dim3(384 / 128, NT), 256, 0, stream>>>(Bb0h, Bb0l, Vrh, Vrl, 384, nullptr,
                                                          nullptr, nullptr, Dy, 128, Xa1h, Xa1l);
    k_y2h2<<<(NN * 32 + 255) / 256, 256, 0, stream>>>(Dy, 0, 128, gat_W + 0 * 32, r2);

    // ---- Level 1 ----
    k_mfma<0, 3><<<dim3(256 / 128, NT), 256, 0, stream>>>(Xa1h, Xa1l, VTh, VTl, 256, filt,
                                                          Bb1h, Bb1l, nullptr, 0, nullptr, nullptr);
    k_mfma<1, 0><<<dim3(768 / 128, NT), 256, 0, stream>>>(Bb1h, Bb1l, Vrh, Vrl, 768, nullptr,
                                                          nullptr, nullptr, Dy, 256, Xa2h, Xa2l);
    k_y2h2<<<(NN * 32 + 255) / 256, 256, 0, stream>>>(Dy, 0, 256, gat_W + 128 * 32, r2);

    // ---- Level 2 (phi-children only) ----
    k_mfma<0, 1><<<dim3(512 / 128, NT), 256, 0, stream>>>(Xa2h, Xa2l, VTh, VTl, 512, filt,
                                                          Bb2h, Bb2l, nullptr, 0, nullptr, nullptr);
    k_mfma<1, 0><<<dim3(512 / 128, NT), 256, 0, stream>>>(Bb2h, Bb2l, Vrh, Vrl, 512, nullptr,
                                                          nullptr, nullptr, Dy, 512, nullptr, nullptr);
    // Y groups [u0,u1,u2,u3]=[z1(y1),z1(y2),z2(y1),z2(y2)] -> rep blocks {3,5,4,6}
    k_y2h2<<<(NN * 32 + 255) / 256, 256, 0, stream>>>(Dy, 0,   128, gat_W + 384 * 32, r2);
    k_y2h2<<<(NN * 32 + 255) / 256, 256, 0, stream>>>(Dy, 128, 128, gat_W + 640 * 32, r2);
    k_y2h2<<<(NN * 32 + 255) / 256, 256, 0, stream>>>(Dy, 256, 128, gat_W + 512 * 32, r2);
    k_y2h2<<<(NN * 32 + 255) / 256, 256, 0, stream>>>(Dy, 384, 128, gat_W + 768 * 32, r2);

    // ---- graph ops ----
    k_agg32<<<(NN * 32 + 255) / 256, 256, 0, stream>>>(r2, rowp, csr, h2);
    k_att<<<(NN * 2 + 255) / 256, 256, 0, stream>>>(h2, att_src, att_dst, asrc, adst);
    k_gat<<<NN, 64, 0, stream>>>(h2, asrc, adst, rowp, csr, gat_b, gout);
    k_mlp<<<(NN * 16 + 255) / 256, 256, 0, stream>>>(gout, mlp_W, mlp_b, g);
    k_final<<<NN, 64, 0, stream>>>(g, rowp, csr, out);
}

// Round 3
// 3345.711 us; speedup vs baseline: 2.6668x; 1.1343x over previous
//
#include <hip/hip_runtime.h>
#include <math.h>

// ---------------------------------------------------------------------------
// fp16x3 split-precision MFMA spectral GEMM chain, round 3.
//  - per-dispatch tile size TM in {32,64,128} to avoid grid starvation
//  - bijective XCD-chunked block swizzle (same-B-panel blocks share an XCD L2)
//  - fused V -> {VT, Vr} hi/lo build (single read of V)
//  - coalesced x@W1 + separate LDS transpose-split
// ---------------------------------------------------------------------------

#define NN     10000
#define KP     10048          // K padded to 157*64
#define NRPAD  10112          // B rows padded to 79*128
#define FIN    128
#define NHID   128
#define PIF    3.14159265358979323846f
#define LOSC   2048.0f
#define ILOSC  (1.0f/2048.0f)

typedef _Float16 f16x8 __attribute__((ext_vector_type(8)));
typedef _Float16 f16x4 __attribute__((ext_vector_type(4)));
typedef float    f32x4 __attribute__((ext_vector_type(4)));

__device__ __forceinline__ float lrelu(float x) { return x > 0.f ? x : 0.2f * x; }

__device__ __forceinline__ void split16(float v, _Float16* hi, _Float16* lo) {
    _Float16 h = (_Float16)v;
    *hi = h;
    *lo = (_Float16)((v - (float)h) * LOSC);
}

__device__ __forceinline__ void gload16(const void* g, void* l) {
    __builtin_amdgcn_global_load_lds((const __attribute__((address_space(1))) void*)g,
                                     (__attribute__((address_space(3))) void*)l, 16, 0, 0);
}

// ---------------- filters: phi(8l), psi(l/4), psi(l/2) per node ----------------
__global__ void k_filters(const float* __restrict__ lamb, float* __restrict__ filt) {
    int i = blockIdx.x * blockDim.x + threadIdx.x;
    if (i >= NN) return;
    float l = lamb[i];
    float a = 8.f * l; if (a == 0.f) a = 1e-7f;
    float ya = 2.f * PIF * a;
    filt[i] = sinf(ya) / ya;
    float b = l * 0.25f; if (b == 0.f) b = 1e-8f;
    filt[NN + i] = sinf(b) / (PIF * b) * (1.f - cosf(b));
    float c = l * 0.5f; if (c == 0.f) c = 1e-8f;
    filt[2 * NN + i] = sinf(c) / (PIF * c) * (1.f - cosf(c));
}

// ---------------- fused V -> VT (transpose) + Vr (copy), f16 hi/lo, pads 0 ----
__global__ __launch_bounds__(256) void k_buildV(const float* __restrict__ V,
                                                _Float16* __restrict__ VTh,
                                                _Float16* __restrict__ VTl,
                                                _Float16* __restrict__ Vrh,
                                                _Float16* __restrict__ Vrl) {
    __shared__ float ts[32][33];
    int t = threadIdx.x;
    int row = t >> 3, c4 = (t & 7) * 4;
    int j0 = blockIdx.x * 32;   // V col block
    int i0 = blockIdx.y * 32;   // V row block
    int i = i0 + row;
    float4 v = make_float4(0.f, 0.f, 0.f, 0.f);
    if (i < NN && j0 + c4 < NN)
        v = *(const float4*)(V + (size_t)i * NN + j0 + c4);
    ts[row][c4 + 0] = v.x; ts[row][c4 + 1] = v.y;
    ts[row][c4 + 2] = v.z; ts[row][c4 + 3] = v.w;
    // Vr[i][j] = V[i][j]
    if (j0 + c4 < KP) {
        f16x4 h, l; _Float16 hh, ll;
        split16(v.x, &hh, &ll); h[0] = hh; l[0] = ll;
        split16(v.y, &hh, &ll); h[1] = hh; l[1] = ll;
        split16(v.z, &hh, &ll); h[2] = hh; l[2] = ll;
        split16(v.w, &hh, &ll); h[3] = hh; l[3] = ll;
        *(f16x4*)(Vrh + (size_t)i * KP + j0 + c4) = h;
        *(f16x4*)(Vrl + (size_t)i * KP + j0 + c4) = l;
    }
    __syncthreads();
    // VT[j][i] = V[i][j]
    if (i0 + c4 < KP) {
        f16x4 h, l; _Float16 hh, ll;
        split16(ts[c4 + 0][row], &hh, &ll); h[0] = hh; l[0] = ll;
        split16(ts[c4 + 1][row], &hh, &ll); h[1] = hh; l[1] = ll;
        split16(ts[c4 + 2][row], &hh, &ll); h[2] = hh; l[2] = ll;
        split16(ts[c4 + 3][row], &hh, &ll); h[3] = hh; l[3] = ll;
        *(f16x4*)(VTh + (size_t)(j0 + row) * KP + i0 + c4) = h;
        *(f16x4*)(VTl + (size_t)(j0 + row) * KP + i0 + c4) = l;
    }
}

// ---------------- h = x @ W1 + b1 (node-major, coalesced) ----------------
__global__ void k_xw1(const float* __restrict__ x, const float* __restrict__ W1,
                      const float* __restrict__ b1, float* __restrict__ h) {
    int t = blockIdx.x * blockDim.x + threadIdx.x;
    if (t >= NN * NHID) return;
    int n = t >> 7, j = t & 127;
    const float* xr = x + (size_t)n * FIN;
    float acc = b1[j];
#pragma unroll 4
    for (int k = 0; k < FIN; k++) acc += xr[k] * W1[k * NHID + j];
    h[t] = acc;
}

// ---------------- hT = h^T as f16 hi/lo [128][KP], pads zeroed ----------------
__global__ __launch_bounds__(256) void k_hsplit(const float* __restrict__ h,
                                                _Float16* __restrict__ hTh,
                                                _Float16* __restrict__ hTl) {
    __shared__ float ts[32][33];
    int t = threadIdx.x;
    int row = t >> 3, c4 = (t & 7) * 4;
    int n0 = blockIdx.x * 32;   // node block
    int c0 = blockIdx.y * 32;   // feature block
    int n = n0 + row;
    float4 v = make_float4(0.f, 0.f, 0.f, 0.f);
    if (n < NN)
        v = *(const float4*)(h + (size_t)n * NHID + c0 + c4);
    ts[row][c4 + 0] = v.x; ts[row][c4 + 1] = v.y;
    ts[row][c4 + 2] = v.z; ts[row][c4 + 3] = v.w;
    __syncthreads();
    f16x4 hh4, ll4; _Float16 hh, ll;
    split16(ts[c4 + 0][row], &hh, &ll); hh4[0] = hh; ll4[0] = ll;
    split16(ts[c4 + 1][row], &hh, &ll); hh4[1] = hh; ll4[1] = ll;
    split16(ts[c4 + 2][row], &hh, &ll); hh4[2] = hh; ll4[2] = ll;
    split16(ts[c4 + 3][row], &hh, &ll); hh4[3] = hh; ll4[3] = ll;
    *(f16x4*)(hTh + (size_t)(c0 + row) * KP + n0 + c4) = hh4;
    *(f16x4*)(hTl + (size_t)(c0 + row) * KP + n0 + c4) = ll4;
}

// ---------------- fp16x3 MFMA GEMM: D[c][n] = sum_k A[c][k] * Bbuf[n][k] ----
// TM: rows per block tile (32/64/128); N tile fixed 128; 4 waves.
// MODE 0 (B = VT): epilogue multiplies by NF filters -> OutH/OutL rows f*C + c
// MODE 1 (B = Vr): epilogue writes Dy fp32 [C][NN]; rows >= absStart also write
// |v| f16 pairs to XaH/XaL (rows c-absStart). Pad cols [NN,KP) written as 0.
template<int MODE, int NF, int TM>
__global__ __launch_bounds__(256, 2) void k_mfma(
    const _Float16* __restrict__ Ah, const _Float16* __restrict__ Al,
    const _Float16* __restrict__ Bh, const _Float16* __restrict__ Bl,
    int C, int MT,
    const float* __restrict__ filt,
    _Float16* __restrict__ OutH, _Float16* __restrict__ OutL,
    float* __restrict__ Dy, int absStart,
    _Float16* __restrict__ XaH, _Float16* __restrict__ XaL)
{
    constexpr int AM   = (TM == 32) ? 2 : 4;    // M fragments per wave
    constexpr int BN   = (TM == 128) ? 4 : 2;   // N fragments per wave
    constexpr int TU_A = TM / 8;                // A staging units (8 rows each)
    constexpr int TU   = (TM + 128) / 8;        // total staging units
    constexpr int UPW  = TU / 4;                // units per wave

    __shared__ __align__(16) _Float16 sAh[TM * 64];
    __shared__ __align__(16) _Float16 sAl[TM * 64];
    __shared__ __align__(16) _Float16 sBh[128 * 64];
    __shared__ __align__(16) _Float16 sBl[128 * 64];

    const int tid  = threadIdx.x;
    const int lane = tid & 63;
    const int wave = tid >> 6;

    // bijective XCD-chunked swizzle (m204): each XCD gets a contiguous chunk
    // of work ids; consecutive work ids share a B panel -> per-XCD L2 reuse.
    const int nwg = (int)gridDim.x;
    const int bid = (int)blockIdx.x;
    const int q = nwg >> 3, r = nwg & 7;
    const int xcd = bid & 7, lid = bid >> 3;
    const int wg = (xcd < r ? xcd * (q + 1) : r * (q + 1) + (xcd - r) * q) + lid;
    const int arow0 = (wg % MT) * TM;
    const int brow0 = (wg / MT) * 128;

    // staging geometry: unit = 8 rows x 64 halves (1KB). source k-chunk
    // pre-swizzled (c_src = c_lds ^ (row&7)) so the linear LDS dest ends up
    // XOR-swizzled for conflict-free ds_read_b128.
    const int lrow = lane >> 3;                  // 0..7
    const int kcol = ((lane & 7) ^ lrow) << 3;   // swizzled k offset (halves)
    size_t offU[UPW]; int ldsU[UPW]; bool aU[UPW];
#pragma unroll
    for (int u = 0; u < UPW; ++u) {
        int g = wave * UPW + u;
        if (g < TU_A) {
            aU[u] = true;  ldsU[u] = g * 512;
            offU[u] = (size_t)(arow0 + g * 8 + lrow) * KP + kcol;
        } else {
            int b = g - TU_A;
            aU[u] = false; ldsU[u] = b * 512;
            offU[u] = (size_t)(brow0 + b * 8 + lrow) * KP + kcol;
        }
    }

    f32x4 acc1[AM][BN], acc2[AM][BN];
#pragma unroll
    for (int i = 0; i < AM; ++i)
#pragma unroll
        for (int j = 0; j < BN; ++j) { acc1[i][j] = 0.f; acc2[i][j] = 0.f; }

    const int fr = lane & 15;
    const int fg = lane >> 4;
    const int wr = (TM == 128) ? (wave >> 1) * 64 : 0;
    const int wc = (TM == 128) ? (wave & 1) * 64 : wave * 32;

    for (int kt = 0; kt < KP / 64; ++kt) {
        const size_t ko = (size_t)kt * 64;
#pragma unroll
        for (int u = 0; u < UPW; ++u) {
            if (aU[u]) {
                gload16(Ah + offU[u] + ko, sAh + ldsU[u]);
                gload16(Al + offU[u] + ko, sAl + ldsU[u]);
            } else {
                gload16(Bh + offU[u] + ko, sBh + ldsU[u]);
                gload16(Bl + offU[u] + ko, sBl + ldsU[u]);
            }
        }
        __syncthreads();   // compiler drains vmcnt before s_barrier
#pragma unroll
        for (int ki = 0; ki < 2; ++ki) {
            const int cs = ((((ki << 2) | fg)) ^ (fr & 7)) << 3;
            f16x8 ah[AM], al[AM], bh[BN], bl[BN];
#pragma unroll
            for (int mt = 0; mt < AM; ++mt) {
                int off = (wr + mt * 16 + fr) * 64 + cs;
                ah[mt] = *(const f16x8*)(sAh + off);
                al[mt] = *(const f16x8*)(sAl + off);
            }
#pragma unroll
            for (int nt = 0; nt < BN; ++nt) {
                int off = (wc + nt * 16 + fr) * 64 + cs;
                bh[nt] = *(const f16x8*)(sBh + off);
                bl[nt] = *(const f16x8*)(sBl + off);
            }
#pragma unroll
            for (int mt = 0; mt < AM; ++mt)
#pragma unroll
                for (int nt = 0; nt < BN; ++nt) {
                    acc1[mt][nt] = __builtin_amdgcn_mfma_f32_16x16x32_f16(ah[mt], bh[nt], acc1[mt][nt], 0, 0, 0);
                    acc2[mt][nt] = __builtin_amdgcn_mfma_f32_16x16x32_f16(ah[mt], bl[nt], acc2[mt][nt], 0, 0, 0);
                    acc2[mt][nt] = __builtin_amdgcn_mfma_f32_16x16x32_f16(al[mt], bh[nt], acc2[mt][nt], 0, 0, 0);
                }
        }
        __syncthreads();
    }

    // epilogue: C/D layout col = lane&15, row = (lane>>4)*4 + reg
    const int ccol  = lane & 15;
    const int crow0 = (lane >> 4) * 4;
#pragma unroll
    for (int nt = 0; nt < BN; ++nt) {
        int n = brow0 + wc + nt * 16 + ccol;
        if (n >= KP) continue;
        bool valid = n < NN;
        float f0 = 0.f, f1 = 0.f, f2 = 0.f;
        if (MODE == 0 && valid) {
            f0 = filt[n];
            if (NF > 1) { f1 = filt[NN + n]; f2 = filt[2 * NN + n]; }
        }
#pragma unroll
        for (int mt = 0; mt < AM; ++mt) {
            int cb = arow0 + wr + mt * 16 + crow0;
#pragma unroll
            for (int r2 = 0; r2 < 4; ++r2) {
                float v = acc1[mt][nt][r2] + acc2[mt][nt][r2] * ILOSC;
                int c = cb + r2;
                if (MODE == 0) {
#pragma unroll
                    for (int f = 0; f < NF; ++f) {
                        float fv = (f == 0 ? f0 : (f == 1 ? f1 : f2)) * v;
                        _Float16 h, l; split16(fv, &h, &l);
                        size_t o = (size_t)(f * C + c) * KP + n;
                        OutH[o] = h; OutL[o] = l;
                    }
                } else {
                    if (valid) Dy[(size_t)c * NN + n] = v;
                    if (c >= absStart) {
                        float av = valid ? fabsf(v) : 0.f;
                        _Float16 h, l; split16(av, &h, &l);
                        size_t o = (size_t)(c - absStart) * KP + n;
                        XaH[o] = h; XaL[o] = l;
                    }
                }
            }
        }
    }
}

// ---------------- r2[n,0:32] += Dy[c0:c0+C, n]^T @ W[0:C, 0:32] ----------------
__global__ void k_y2h2(const float* __restrict__ Yt, int c0, int C,
                       const float* __restrict__ Wp, float* __restrict__ r2) {
    int t = blockIdx.x * blockDim.x + threadIdx.x;
    if (t >= NN * 32) return;
    int n = t >> 5, j = t & 31;
    float acc = 0.f;
    for (int k = 0; k < C; k++) acc += Yt[(size_t)(c0 + k) * NN + n] * Wp[k * 32 + j];
    r2[t] += acc;
}

__global__ void k_zero_f(float* p, int n) {
    int i = blockIdx.x * blockDim.x + threadIdx.x;
    if (i < n) p[i] = 0.f;
}

// ---------------- CSR build ----------------
__global__ void k_zero_int(int* p, int n) {
    int i = blockIdx.x * blockDim.x + threadIdx.x;
    if (i < n) p[i] = 0;
}
__global__ void k_count(const int* __restrict__ dst, int* __restrict__ deg, int E) {
    int e = blockIdx.x * blockDim.x + threadIdx.x;
    if (e < E) atomicAdd(&deg[dst[e]], 1);
}
__global__ __launch_bounds__(1024) void k_scan(const int* __restrict__ deg,
                                               int* __restrict__ rowp, int* __restrict__ cur, int E) {
    __shared__ int s[1024];
    int t = threadIdx.x;
    int base = t * 10;
    int sum = 0;
    for (int i = 0; i < 10; i++) { int idx = base + i; if (idx < NN) sum += deg[idx]; }
    s[t] = sum; __syncthreads();
    for (int off = 1; off < 1024; off <<= 1) {
        int v = (t >= off) ? s[t - off] : 0;
        __syncthreads();
        s[t] += v;
        __syncthreads();
    }
    int run = (t > 0) ? s[t - 1] : 0;
    for (int i = 0; i < 10; i++) {
        int idx = base + i;
        if (idx < NN) { rowp[idx] = run; cur[idx] = run; run += deg[idx]; }
    }
    if (t == 0) rowp[NN] = E;
}
__global__ void k_fill(const int* __restrict__ src, const int* __restrict__ dst,
                       int* __restrict__ cur, int* __restrict__ csr, int E) {
    int e = blockIdx.x * blockDim.x + threadIdx.x;
    if (e < E) {
        int d = dst[e];
        int p = atomicAdd(&cur[d], 1);
        csr[p] = src[e];
    }
}

// ---------------- h2[n,j] = sum over in-edges r2[src,j]  (32 feat) ----------------
__global__ void k_agg32(const float* __restrict__ r2, const int* __restrict__ rowp,
                        const int* __restrict__ csr, float* __restrict__ h2) {
    int t = blockIdx.x * blockDim.x + threadIdx.x;
    if (t >= NN * 32) return;
    int n = t >> 5, j = t & 31;
    int s0 = rowp[n], s1 = rowp[n + 1];
    float a = 0.f;
    for (int e = s0; e < s1; e++) a += r2[(size_t)csr[e] * 32 + j];
    h2[t] = a;
}

// ---------------- attention logits per node/head ----------------
__global__ void k_att(const float* __restrict__ h2, const float* __restrict__ att_s,
                      const float* __restrict__ att_d, float* __restrict__ asrc,
                      float* __restrict__ adst) {
    int t = blockIdx.x * blockDim.x + threadIdx.x;
    if (t >= NN * 2) return;
    int n = t >> 1, hh = t & 1;
    const float* hr = h2 + (size_t)n * 32 + hh * 16;
    float s = 0.f, d = 0.f;
    for (int c = 0; c < 16; c++) {
        float v = hr[c];
        s += v * att_s[hh * 16 + c];
        d += v * att_d[hh * 16 + c];
    }
    asrc[t] = s; adst[t] = d;
}

// ---------------- GAT softmax-aggregate, one 64-thread block per dst ----------------
__global__ __launch_bounds__(64) void k_gat(const float* __restrict__ h2,
                                            const float* __restrict__ asrc,
                                            const float* __restrict__ adst,
                                            const int* __restrict__ rowp,
                                            const int* __restrict__ csr,
                                            const float* __restrict__ bias,
                                            float* __restrict__ gout) {
    int d = blockIdx.x, lane = threadIdx.x;
    int s0 = rowp[d], s1 = rowp[d + 1];
    __shared__ float sm[2], sden[2];
    int hh = lane >> 5;
    float adh = adst[d * 2 + hh];
    float eself = lrelu(asrc[d * 2 + hh] + adh);
    float m = eself;
    for (int j = s0 + (lane & 31); j < s1; j += 32) {
        int s = csr[j];
        m = fmaxf(m, lrelu(asrc[s * 2 + hh] + adh));
    }
    for (int off = 16; off; off >>= 1) m = fmaxf(m, __shfl_xor(m, off, 32));
    float den = ((lane & 31) == 0) ? expf(eself - m) : 0.f;
    for (int j = s0 + (lane & 31); j < s1; j += 32) {
        int s = csr[j];
        den += expf(lrelu(asrc[s * 2 + hh] + adh) - m);
    }
    for (int off = 16; off; off >>= 1) den += __shfl_xor(den, off, 32);
    if ((lane & 31) == 0) { sm[hh] = m; sden[hh] = den; }
    __syncthreads();
    int f = lane & 31;
    int h3 = f >> 4;
    float mh = sm[h3], dh = sden[h3];
    float ad3 = adst[d * 2 + h3];
    float acc = 0.f;
    for (int j = s0 + (lane >> 5); j < s1; j += 2) {
        int s = csr[j];
        float e = lrelu(asrc[s * 2 + h3] + ad3);
        acc += expf(e - mh) * h2[(size_t)s * 32 + f];
    }
    if ((lane >> 5) == 0) {
        float es = lrelu(asrc[d * 2 + h3] + ad3);
        acc += expf(es - mh) * h2[(size_t)d * 32 + f];
    }
    acc += __shfl_down(acc, 32, 64);
    if (lane < 32) gout[(size_t)d * 32 + f] = acc / dh + bias[f];
}

// ---------------- g = elu(gout) @ mlp_W + mlp_b ----------------
__global__ void k_mlp(const float* __restrict__ gout, const float* __restrict__ mw,
                      const float* __restrict__ mb, float* __restrict__ g) {
    int t = blockIdx.x * blockDim.x + threadIdx.x;
    if (t >= NN * 16) return;
    int n = t >> 4, j = t & 15;
    const float* gr = gout + (size_t)n * 32;
    float acc = mb[j];
    for (int k = 0; k < 32; k++) {
        float v = gr[k];
        v = v > 0.f ? v : expm1f(v);
        acc += v * mw[k * 16 + j];
    }
    g[t] = acc;
}

// ---------------- final edge-sum + log_softmax (fp32 output) ----------------
__global__ __launch_bounds__(64) void k_final(const float* __restrict__ g,
                                              const int* __restrict__ rowp,
                                              const int* __restrict__ csr,
                                              float* __restrict__ out) {
    int d = blockIdx.x, lane = threadIdx.x;
    int s0 = rowp[d], s1 = rowp[d + 1];
    int f = lane & 15, grp = lane >> 4;
    float acc = 0.f;
    for (int j = s0 + grp; j < s1; j += 4) acc += g[(size_t)csr[j] * 16 + f];
    acc += __shfl_xor(acc, 16, 64);
    acc += __shfl_xor(acc, 32, 64);
    float mx = acc;
    for (int off = 8; off; off >>= 1) mx = fmaxf(mx, __shfl_xor(mx, off, 16));
    float ex = expf(acc - mx);
    float se = ex;
    for (int off = 8; off; off >>= 1) se += __shfl_xor(se, off, 16);
    if (lane < 16) out[(size_t)d * 16 + f] = acc - mx - logf(se);
}

extern "C" void kernel_launch(void* const* d_in, const int* in_sizes, int n_in,
                              void* d_out, int out_size, void* d_ws, size_t ws_size,
                              hipStream_t stream) {
    (void)n_in; (void)out_size; (void)ws_size;
    const float* x       = (const float*)d_in[0];
    const int*   ei      = (const int*)d_in[1];
    const float* lamb    = (const float*)d_in[2];
    const float* V       = (const float*)d_in[3];
    const float* W1      = (const float*)d_in[4];
    const float* b1      = (const float*)d_in[5];
    const float* gat_W   = (const float*)d_in[6];
    const float* att_src = (const float*)d_in[7];
    const float* att_dst = (const float*)d_in[8];
    const float* gat_b   = (const float*)d_in[9];
    const float* mlp_W   = (const float*)d_in[10];
    const float* mlp_b   = (const float*)d_in[11];
    float* out = (float*)d_out;
    const int E = in_sizes[1] / 2;
    const int* e_src = ei;
    const int* e_dst = ei + E;

    char* w = (char*)d_ws;
    auto alloc = [&](size_t bytes) { void* p = (void*)w; w += (bytes + 255) & ~(size_t)255; return p; };
    _Float16* VTh  = (_Float16*)alloc((size_t)NRPAD * KP * 2);   // 203 MB
    _Float16* VTl  = (_Float16*)alloc((size_t)NRPAD * KP * 2);   // 203 MB
    _Float16* Vrh  = (_Float16*)alloc((size_t)NRPAD * KP * 2);   // 203 MB
    _Float16* Vrl  = (_Float16*)alloc((size_t)NRPAD * KP * 2);   // 203 MB
    _Float16* hTh  = (_Float16*)alloc((size_t)128 * KP * 2);
    _Float16* hTl  = (_Float16*)alloc((size_t)128 * KP * 2);
    _Float16* Bb0h = (_Float16*)alloc((size_t)384 * KP * 2);
    _Float16* Bb0l = (_Float16*)alloc((size_t)384 * KP * 2);
    _Float16* Xa1h = (_Float16*)alloc((size_t)256 * KP * 2);
    _Float16* Xa1l = (_Float16*)alloc((size_t)256 * KP * 2);
    _Float16* Bb1h = (_Float16*)alloc((size_t)768 * KP * 2);
    _Float16* Bb1l = (_Float16*)alloc((size_t)768 * KP * 2);
    _Float16* Xa2h = (_Float16*)alloc((size_t)512 * KP * 2);
    _Float16* Xa2l = (_Float16*)alloc((size_t)512 * KP * 2);
    _Float16* Bb2h = (_Float16*)alloc((size_t)512 * KP * 2);
    _Float16* Bb2l = (_Float16*)alloc((size_t)512 * KP * 2);
    float* Dy   = (float*)alloc((size_t)768 * NN * 4);           // 30.7 MB
    float* h    = (float*)alloc((size_t)NN * NHID * 4);
    float* r2   = (float*)alloc((size_t)NN * 32 * 4);
    float* h2   = (float*)alloc((size_t)NN * 32 * 4);
    float* asrc = (float*)alloc((size_t)NN * 2 * 4);
    float* adst = (float*)alloc((size_t)NN * 2 * 4);
    float* gout = (float*)alloc((size_t)NN * 32 * 4);
    float* g    = (float*)alloc((size_t)NN * 16 * 4);
    float* filt = (float*)alloc((size_t)3 * NN * 4);
    int* deg    = (int*)alloc((size_t)NN * 4);
    int* rowp   = (int*)alloc((size_t)(NN + 1) * 4);
    int* cur    = (int*)alloc((size_t)NN * 4);
    int* csr    = (int*)alloc((size_t)E * 4);

    // CSR build
    k_zero_int<<<(NN + 255) / 256, 256, 0, stream>>>(deg, NN);
    k_count<<<(E + 255) / 256, 256, 0, stream>>>(e_dst, deg, E);
    k_scan<<<1, 1024, 0, stream>>>(deg, rowp, cur, E);
    k_fill<<<(E + 255) / 256, 256, 0, stream>>>(e_src, e_dst, cur, csr, E);

    k_filters<<<(NN + 255) / 256, 256, 0, stream>>>(lamb, filt);
    k_buildV<<<dim3(NRPAD / 32, NRPAD / 32), 256, 0, stream>>>(V, VTh, VTl, Vrh, Vrl);
    k_xw1<<<(NN * NHID + 255) / 256, 256, 0, stream>>>(x, W1, b1, h);
    k_hsplit<<<dim3(KP / 32, NHID / 32), 256, 0, stream>>>(h, hTh, hTl);
    k_zero_f<<<(NN * 32 + 255) / 256, 256, 0, stream>>>(r2, NN * 32);

    const int NT = NRPAD / 128;  // 79 node-panel tiles

    // ---- Level 0 ----
    k_mfma<0, 3, 32><<<4 * NT, 256, 0, stream>>>(hTh, hTl, VTh, VTl, 128, 4, filt,
                                                 Bb0h, Bb0l, nullptr, 0, nullptr, nullptr);
    k_mfma<1, 0, 64><<<6 * NT, 256, 0, stream>>>(Bb0h, Bb0l, Vrh, Vrl, 384, 6, nullptr,
                                                 nullptr, nullptr, Dy, 128, Xa1h, Xa1l);
    k_y2h2<<<(NN * 32 + 255) / 256, 256, 0, stream>>>(Dy, 0, 128, gat_W + 0 * 32, r2);

    // ---- Level 1 ----
    k_mfma<0, 3, 32><<<8 * NT, 256, 0, stream>>>(Xa1h, Xa1l, VTh, VTl, 256, 8, filt,
                                                 Bb1h, Bb1l, nullptr, 0, nullptr, nullptr);
    k_mfma<1, 0, 128><<<6 * NT, 256, 0, stream>>>(Bb1h, Bb1l, Vrh, Vrl, 768, 6, nullptr,
                                                  nullptr, nullptr, Dy, 256, Xa2h, Xa2l);
    k_y2h2<<<(NN * 32 + 255) / 256, 256, 0, stream>>>(Dy, 0, 256, gat_W + 128 * 32, r2);

    // ---- Level 2 (phi-children only) ----
    k_mfma<0, 1, 64><<<8 * NT, 256, 0, stream>>>(Xa2h, Xa2l, VTh, VTl, 512, 8, filt,
                                                 Bb2h, Bb2l, nullptr, 0, nullptr, nullptr);
    k_mfma<1, 0, 64><<<8 * NT, 256, 0, stream>>>(Bb2h, Bb2l, Vrh, Vrl, 512, 8, nullptr,
                                                 nullptr, nullptr, Dy, 512, nullptr, nullptr);
    // Y groups [u0,u1,u2,u3]=[z1(y1),z1(y2),z2(y1),z2(y2)] -> rep blocks {3,5,4,6}
    k_y2h2<<<(NN * 32 + 255) / 256, 256, 0, stream>>>(Dy, 0,   128, gat_W + 384 * 32, r2);
    k_y2h2<<<(NN * 32 + 255) / 256, 256, 0, stream>>>(Dy, 128, 128, gat_W + 640 * 32, r2);
    k_y2h2<<<(NN * 32 + 255) / 256, 256, 0, stream>>>(Dy, 256, 128, gat_W + 512 * 32, r2);
    k_y2h2<<<(NN * 32 + 255) / 256, 256, 0, stream>>>(Dy, 384, 128, gat_W + 768 * 32, r2);

    // ---- graph ops ----
    k_agg32<<<(NN * 32 + 255) / 256, 256, 0, stream>>>(r2, rowp, csr, h2);
    k_att<<<(NN * 2 + 255) / 256, 256, 0, stream>>>(h2, att_src, att_dst, asrc, adst);
    k_gat<<<NN, 64, 0, stream>>>(h2, asrc, adst, rowp, csr, gat_b, gout);
    k_mlp<<<(NN * 16 + 255) / 256, 256, 0, stream>>>(gout, mlp_W, mlp_b, g);
    k_final<<<NN, 64, 0, stream>>>(g, rowp, csr, out);
}